// Round 8
// baseline (3866.537 us; speedup 1.0000x reference)
//
#include <hip/hip_runtime.h>
#include <float.h>

#define NEMB 1024
#define EDIM 256
#define BM   64     // rows per block; 1 row per lane
#define HW   4096   // 64*64
#define NT   1024   // 16 waves
#define NW   (NT / 64)
#define NB   16     // codewords per accumulator group (4 groups of 16)
#define ZQ_ELEMS 33554432   // 32*256*4096

// numpy FLOAT_pairwise_sum of squares, n=256: two 128-blocks, 8 accumulators
// r[j] += a[8i+j], tree-combine ((r0+r1)+(r2+r3))+((r4+r5)+(r6+r7)), then
// blk0+blk1. Squares rounded separately (contract off).
template <typename F>
__device__ __forceinline__ float np_sumsq_256(F get) {
#pragma clang fp contract(off)
    float blk[2];
#pragma unroll
    for (int h = 0; h < 2; ++h) {
        const int base = h * 128;
        float r[8];
#pragma unroll
        for (int j = 0; j < 8; ++j) {
            float v = get(base + j);
            r[j] = v * v;
        }
        for (int i = 8; i < 128; i += 8) {
#pragma unroll
            for (int j = 0; j < 8; ++j) {
                float v = get(base + i + j);
                float p = v * v;
                r[j] = r[j] + p;
            }
        }
        blk[h] = ((r[0] + r[1]) + (r[2] + r[3])) + ((r[4] + r[5]) + (r[6] + r[7]));
    }
    return blk[0] + blk[1];
}

__global__ __launch_bounds__(256) void esq_kernel(const float* __restrict__ emb,
                                                  float* __restrict__ esq) {
    int n = blockIdx.x * 256 + threadIdx.x;
    const float* e = emb + (size_t)n * EDIM;
    esq[n] = np_sumsq_256([&](int k) { return e[k]; });
}

// z tile, PAIR-INTERLEAVED: z(k,r) at word (k>>1)*128 + 2*r + (k&1); lane r
// reads float2 {z(2m,r),z(2m+1,r)} -> conflict-free ds_read_b64 (R1-proven).
//
// ROUND-8: vector-path emb, CO-DESIGNED for the hard 64-VGPR cap this
// toolchain enforces (observed 5 rounds straight; R2/R5/R7 all spilled the
// moment demand exceeded ~64). Why vector path: SMEM returns OOO, so any
// s_load consume forces lgkmcnt(0), draining all in-flight prefetches (ds
// AND smem) -> scalar emb can never pipeline; that drain = the stable ~35%
// no-issue of R0-R5. VMEM is in-order (counted vmcnt), lands in VGPRs, no
// SGPR wall. To FIT the budget: BM=64 / 1 row per lane -> acc[16] is 16
// regs (NB=16 also cuts z-LDS bandwidth to ~38% duty, off the contention
// knee); 64 KiB LDS -> 2 blocks/CU -> 8 waves/SIMD (2x TLP to hide emb L2
// latency); emb addressed via 4 VGPR base pointers + compile-time
// immediate offsets ((j&3)*1024+kc*4 <= 4080). Opaque-zero keeps the
// address formally divergent -> global_load_dwordx4, uniform addr = one
// line-txn broadcast. Budget ~55 VGPRs.
__global__ __launch_bounds__(NT, 4) void vq_kernel(const float* __restrict__ z,
                                                   const float* __restrict__ emb,
                                                   const float* __restrict__ esq,
                                                   float* __restrict__ out) {
    __shared__ float zl[BM * EDIM];   // 64 KiB -> 2 blocks/CU, 32 waves/CU

    const int t   = threadIdx.x;
    const int blk = blockIdx.x;           // 2048 blocks: 64 per batch image
    const int b   = blk >> 6;
    const int hw0 = (blk & 63) * BM;
    const float* zbase = z + (size_t)b * EDIM * HW;

    // ---- stage z tile: 4096 float4, 4 per thread, coalesced along hw ----
#pragma unroll
    for (int pass = 0; pass < 4; ++pass) {
        int f4 = pass * NT + t;
        int r4 = (f4 & 15) * 4;
        int k  = f4 >> 4;
        float4 v = *(const float4*)(zbase + (size_t)k * HW + hw0 + r4);
        int w = (k >> 1) * 128 + 2 * r4 + (k & 1);
        zl[w + 0] = v.x;
        zl[w + 2] = v.y;
        zl[w + 4] = v.z;
        zl[w + 6] = v.w;
    }
    __syncthreads();

    const int r = t & 63;                 // my row (lane id)
    const float* zr = zl + 2 * r;
    // z_sq with exact numpy pairwise semantics (redundant per wave; cheap)
    const float zsq = np_sumsq_256([&](int k) { return zr[(k >> 1) * 128 + (k & 1)]; });

    // wave id -> 64-codeword quota
    const int q = __builtin_amdgcn_readfirstlane(t >> 6);

    // Opaque zero in a VGPR: compiler cannot prove uniformity -> emb loads
    // stay on the vector-memory path (global_load, counted vmcnt).
    int lzero;
    asm("v_mov_b32 %0, 0" : "=v"(lzero));
    const float* embv = emb + lzero;

    float best = FLT_MAX;
    int   bidx = 0;

#pragma unroll 1
    for (int g = 0; g < 4; ++g) {
        const int n0 = q * 64 + g * NB;
        // 4 divergent base pointers; j within each covered by imm offsets.
        const float* p0 = embv + (size_t)n0 * EDIM;
        const float* p1 = p0 + 4 * EDIM;
        const float* p2 = p0 + 8 * EDIM;
        const float* p3 = p0 + 12 * EDIM;

        float acc[NB];
#pragma unroll
        for (int j = 0; j < NB; ++j) acc[j] = 0.f;

#pragma unroll 1
        for (int kc = 0; kc < EDIM; kc += 4) {
            // z chunk: 4 k for my row = 2 conflict-free ds_read_b64
            const int m0 = kc >> 1;
            float2 z0 = *(const float2*)(zr + (m0 + 0) * 128);
            float2 z1 = *(const float2*)(zr + (m0 + 1) * 128);
            // e_z: strictly sequential fp32 FMA over k per codeword
            // (kc-ascending, ef.x..ef.w) — bit-identical numpy order.
#pragma unroll
            for (int j = 0; j < NB; ++j) {
                const float* pj = (j < 4) ? p0 : (j < 8) ? p1 : (j < 12) ? p2 : p3;
                float4 ef = *(const float4*)(pj + (j & 3) * EDIM + kc);
                float a = acc[j];
                a = fmaf(z0.x, ef.x, a);
                a = fmaf(z0.y, ef.y, a);
                a = fmaf(z1.x, ef.z, a);
                a = fmaf(z1.y, ef.w, a);
                acc[j] = a;
            }
        }

#pragma unroll
        for (int j = 0; j < NB; ++j) {
            // numpy: dist = RN( RN(zsq+esq) - 2*ez ); 2*ez exact -> fma form
            // is bit-identical.
            float t1 = zsq + esq[n0 + j];
            float d  = fmaf(-2.f, acc[j], t1);
            if (d < best) { best = d; bidx = n0 + j; }   // strict <: first-index
        }
    }

    // ---- cross-wave (min,idx) reduction, reusing zl ----
    __syncthreads();                        // all zl reads done
    float* rv   = zl;                       // [1024] best value
    int*   ri   = (int*)(zl + NT);          // [1024] best idx
    int*   ifin = (int*)(zl + 2 * NT);      // [64]   final idx per row
    rv[t] = best;
    ri[t] = bidx;
    __syncthreads();
    if (t < 64) {
        float bv = rv[t];
        int   bi = ri[t];
#pragma unroll
        for (int w = 1; w < NW; ++w) {
            float v = rv[t + 64 * w];
            int   i = ri[t + 64 * w];
            // waves cover ascending idx ranges; strict < keeps lowest idx
            if (v < bv) { bv = v; bi = i; }
        }
        ifin[t] = bi;
        out[(size_t)ZQ_ELEMS + (size_t)blk * BM + t] = (float)bi;  // idx as float
    }
    __syncthreads();

    // ---- z_q[b][c][hw] = emb[idx[hw]][c], coalesced float4 along hw ----
    float* zq = out + (size_t)b * EDIM * HW;
#pragma unroll
    for (int pass = 0; pass < 4; ++pass) {
        int f4 = pass * NT + t;
        int r4 = (f4 & 15) * 4;
        int c  = f4 >> 4;
        float4 v;
        v.x = emb[(size_t)ifin[r4 + 0] * EDIM + c];
        v.y = emb[(size_t)ifin[r4 + 1] * EDIM + c];
        v.z = emb[(size_t)ifin[r4 + 2] * EDIM + c];
        v.w = emb[(size_t)ifin[r4 + 3] * EDIM + c];
        *(float4*)(zq + (size_t)c * HW + hw0 + r4) = v;
    }
}

extern "C" void kernel_launch(void* const* d_in, const int* in_sizes, int n_in,
                              void* d_out, int out_size, void* d_ws, size_t ws_size,
                              hipStream_t stream) {
    const float* z   = (const float*)d_in[0];   // [32,256,64,64]
    const float* emb = (const float*)d_in[1];   // [1024,256]
    float* out = (float*)d_out;                 // 33554432 z_q + 131072 idx (as float)
    float* esq = (float*)d_ws;                  // 1024 floats scratch

    esq_kernel<<<NEMB / 256, 256, 0, stream>>>(emb, esq);
    vq_kernel<<<131072 / BM, NT, 0, stream>>>(z, emb, esq, out);
}